// Round 6
// baseline (388.404 us; speedup 1.0000x reference)
//
#include <hip/hip_runtime.h>

#define KOFF 9
#define N_PTS 262144
#define D 32
#define BINS 512
#define ROWS_PER_BIN 512       // N_PTS / BINS
#define TILE_ROWS 513          // + dump row for sentinel entries
#define NXCD 8
#define SUBCAP 80              // per (xcd,bin,k) capacity; mean<=64 worst-k
#define NSEG (KOFF * NXCD)     // 72 segments per bin
#define OVER_CAP 131072
#define SENT (512u << 18)

typedef __attribute__((ext_vector_type(4))) float f32x4;
typedef __attribute__((ext_vector_type(8))) short short8;

__device__ inline short f2bf(float f) {      // round-to-nearest-even f32->bf16
    unsigned u = __float_as_uint(f);
    u = (u + 0x7fffu + ((u >> 16) & 1u)) >> 16;
    return (short)u;
}

// ---------- fill: XCD-local binning by (xcd, orow>>9, k) ----------
__global__ void __launch_bounds__(256)
fill_kernel(const int* __restrict__ indice_pairs,
            const int* __restrict__ indice_pair_num,
            int* __restrict__ counts,          // [NXCD][BINS*KOFF]
            unsigned int* __restrict__ buckets,// [NXCD][BINS*KOFF][SUBCAP]
            uint2* __restrict__ overlist,
            int* __restrict__ over_n) {
    const int k = blockIdx.y;
    const int n_k = indice_pair_num[k];
    if (blockIdx.x * 256 >= n_k) return;
    const int p = blockIdx.x * 256 + threadIdx.x;
    if (p >= n_k) return;

    unsigned xcd;
    asm volatile("s_getreg_b32 %0, hwreg(HW_REG_XCC_ID)" : "=s"(xcd));
    xcd &= 7;                                   // safety: stay in range

    int irow = indice_pairs[(size_t)k * N_PTS + p];
    int orow = indice_pairs[(size_t)(KOFF + k) * N_PTS + p];
    int bin = orow >> 9, olow = orow & 511;
    int idx = (int)xcd * (BINS * KOFF) + bin * KOFF + k;
    int slot = atomicAdd(&counts[idx], 1);
    if (slot < SUBCAP) {
        buckets[(size_t)idx * SUBCAP + slot] = (unsigned)irow | ((unsigned)olow << 18);
    } else {
        int s2 = atomicAdd(over_n, 1);
        if (s2 < OVER_CAP) overlist[s2] = make_uint2((unsigned)irow | ((unsigned)k << 18),
                                                     (unsigned)orow);
    }
}

// ---------- phase 2: per-bin LDS-tile accumulate, segment-per-wave ----------
#define SEG_INFO(J, CNT, BK, KV) { int s_ = start + (J); KV = s_ >> 3; int x_ = s_ & 7; \
    int idx_ = x_ * (BINS * KOFF) + bin * KOFF + KV; \
    CNT = counts[idx_]; CNT = CNT < SUBCAP ? CNT : SUBCAP; \
    BK = buckets + (size_t)idx_ * SUBCAP; }

#define LOAD_ENT(BK, CNT, E, G) E = ((G)*16 + arow < (CNT)) ? (BK)[(G)*16 + arow] : SENT;

#define LOAD_FEAT(E, F0, F1, G, CNT) if ((G)*16 < (CNT)) { \
    const float* fp_ = feat + ((size_t)((E) & 0x3ffff) << 5) + hoff; \
    F0 = *(const f32x4*)fp_; F1 = *(const f32x4*)(fp_ + 4); }

#define COMPUTE(E, F0, F1, G, CNT) if ((G)*16 < (CNT)) { \
    short8 af_; \
    _Pragma("unroll") for (int j_ = 0; j_ < 4; ++j_) { af_[j_] = f2bf(F0[j_]); af_[j_+4] = f2bf(F1[j_]); } \
    f32x4 a0_ = __builtin_amdgcn_mfma_f32_16x16x32_bf16(af_, bfa, z, 0, 0, 0); \
    f32x4 a1_ = __builtin_amdgcn_mfma_f32_16x16x32_bf16(af_, bfb, z, 0, 0, 0); \
    _Pragma("unroll") for (int rg_ = 0; rg_ < 4; ++rg_) { \
        int crow_ = ((lane >> 4) << 2) + rg_; \
        int entc_ = __builtin_amdgcn_ds_bpermute(crow_ << 2, (int)(E)); \
        int rl_ = ((unsigned)entc_ >> 18) & 0x3ff; \
        int sw_ = ((rl_ >> 2) & 1) << 4; \
        atomicAdd(&tile[rl_ * D + (arow ^ sw_)], a0_[rg_]); \
        atomicAdd(&tile[rl_ * D + ((arow + 16) ^ sw_)], a1_[rg_]); } }

__global__ void __launch_bounds__(1024, 4)
phase2_kernel(const float* __restrict__ feat,
              const float* __restrict__ weight,
              const float* __restrict__ bias,
              const int* __restrict__ counts,
              const unsigned int* __restrict__ buckets,
              float* __restrict__ out) {
    __shared__ f32x4 tile4[TILE_ROWS * D / 4];      // 65,664 B accumulator
    float* tile = (float*)tile4;

    const int bin  = blockIdx.x;
    const int tid  = threadIdx.x;
    const int wave = tid >> 6;
    const int lane = tid & 63;

    f32x4 z = {0.f, 0.f, 0.f, 0.f};
    for (int i = tid; i < TILE_ROWS * D / 4; i += 1024) tile4[i] = z;
    __syncthreads();

    const int arow = lane & 15;                 // A row / entry index within group
    const int hoff = (lane >> 4) << 3;          // k-dim chunk: 8 floats

    // wave -> contiguous segment run: waves 0-7 get 5 segs, 8-15 get 4 (72 total)
    const int start = (wave < 8) ? wave * 5 : 40 + (wave - 8) * 4;
    const int nseg  = (wave < 8) ? 5 : 4;

    int kcur, cnt_cur; const unsigned* bk_cur;
    SEG_INFO(0, cnt_cur, bk_cur, kcur);
    unsigned e0, e1, e2, e3, e4;
    LOAD_ENT(bk_cur, cnt_cur, e0, 0) LOAD_ENT(bk_cur, cnt_cur, e1, 1)
    LOAD_ENT(bk_cur, cnt_cur, e2, 2) LOAD_ENT(bk_cur, cnt_cur, e3, 3)
    LOAD_ENT(bk_cur, cnt_cur, e4, 4)

    short8 bfa = {0,0,0,0,0,0,0,0}, bfb = {0,0,0,0,0,0,0,0};
    int kloaded = -1;

#pragma unroll 1
    for (int j = 0; j < nseg; ++j) {
        // prefetch next segment's entries (independent loads, issue early)
        int knext = kcur, cnt_next = 0; const unsigned* bk_next = bk_cur;
        unsigned n0 = SENT, n1 = SENT, n2 = SENT, n3 = SENT, n4 = SENT;
        if (j + 1 < nseg) {
            SEG_INFO(j + 1, cnt_next, bk_next, knext);
            LOAD_ENT(bk_next, cnt_next, n0, 0) LOAD_ENT(bk_next, cnt_next, n1, 1)
            LOAD_ENT(bk_next, cnt_next, n2, 2) LOAD_ENT(bk_next, cnt_next, n3, 3)
            LOAD_ENT(bk_next, cnt_next, n4, 4)
        }

        // B fragments for current k (runs of same-k segments -> ~2 loads/wave)
        if (kloaded != kcur) {
            const float* wp0 = weight + (size_t)arow * (KOFF * D) + kcur * D + hoff;
            const float* wp1 = wp0 + 16 * (KOFF * D);
            f32x4 w0 = *(const f32x4*)wp0, w1 = *(const f32x4*)(wp0 + 4);
            f32x4 w2 = *(const f32x4*)wp1, w3 = *(const f32x4*)(wp1 + 4);
#pragma unroll
            for (int jq = 0; jq < 4; ++jq) {
                bfa[jq] = f2bf(w0[jq]); bfa[jq + 4] = f2bf(w1[jq]);
                bfb[jq] = f2bf(w2[jq]); bfb[jq + 4] = f2bf(w3[jq]);
            }
            kloaded = kcur;
        }

        // issue ALL feat gathers for this segment's (<=5) groups -> deep MLP
        f32x4 fa0 = z, fa1 = z, fb0 = z, fb1 = z, fc0 = z, fc1 = z,
              fd0 = z, fd1 = z, fe0 = z, fe1 = z;
        LOAD_FEAT(e0, fa0, fa1, 0, cnt_cur)
        LOAD_FEAT(e1, fb0, fb1, 1, cnt_cur)
        LOAD_FEAT(e2, fc0, fc1, 2, cnt_cur)
        LOAD_FEAT(e3, fd0, fd1, 3, cnt_cur)
        LOAD_FEAT(e4, fe0, fe1, 4, cnt_cur)

        COMPUTE(e0, fa0, fa1, 0, cnt_cur)
        COMPUTE(e1, fb0, fb1, 1, cnt_cur)
        COMPUTE(e2, fc0, fc1, 2, cnt_cur)
        COMPUTE(e3, fd0, fd1, 3, cnt_cur)
        COMPUTE(e4, fe0, fe1, 4, cnt_cur)

        e0 = n0; e1 = n1; e2 = n2; e3 = n3; e4 = n4;
        cnt_cur = cnt_next; bk_cur = bk_next; kcur = knext;
    }
    __syncthreads();

    // stream tile + bias to out (coalesced, unswizzled)
    f32x4 b4 = ((const f32x4*)bias)[tid & 7];
    for (int i = tid; i < ROWS_PER_BIN * 8; i += 1024) {
        int row = i >> 3, c4 = i & 7;
        int sc4 = c4 ^ (((row >> 2) & 1) << 2);     // f32x4-level unswizzle
        f32x4 v = tile4[row * 8 + sc4];
        v += b4;
        *(f32x4*)&out[((size_t)(bin * ROWS_PER_BIN + row)) * D + c4 * 4] = v;
    }
}

// ---------- rare overflow cleanup (after phase2 store) ----------
__global__ void overflow_kernel(const float* __restrict__ feat,
                                const float* __restrict__ weight,
                                const uint2* __restrict__ overlist,
                                const int* __restrict__ over_n,
                                float* __restrict__ out) {
    int n = *over_n;
    n = n < OVER_CAP ? n : OVER_CAP;
    for (int i = blockIdx.x * blockDim.x + threadIdx.x; i < n;
         i += gridDim.x * blockDim.x) {
        uint2 e = overlist[i];
        int irow = e.x & 0x3ffff, k = (e.x >> 18) & 15, orow = (int)e.y;
        float fr[D];
#pragma unroll
        for (int c = 0; c < D; c += 4)
            *(f32x4*)&fr[c] = *(const f32x4*)&feat[(size_t)irow * D + c];
#pragma unroll 1
        for (int dd = 0; dd < D; ++dd) {
            float a = 0.f;
#pragma unroll
            for (int c = 0; c < D; ++c)
                a += fr[c] * weight[dd * (KOFF * D) + k * D + c];
            atomicAdd(&out[(size_t)orow * D + dd], a);
        }
    }
}

// ---------- fallback path (R1): direct scatter with global atomics ----------
__global__ void bias_init_kernel(const float* __restrict__ bias,
                                 float* __restrict__ out) {
    int i = blockIdx.x * blockDim.x + threadIdx.x;
    float4 b = ((const float4*)bias)[i & 7];
    ((float4*)out)[i] = b;
}

#define PPB 8
__global__ void __launch_bounds__(256)
scatter_conv_kernel(const float* __restrict__ feat,
                    const float* __restrict__ weight,
                    const int* __restrict__ indice_pairs,
                    const int* __restrict__ indice_pair_num,
                    float* __restrict__ out) {
    const int k   = blockIdx.y;
    const int n_k = indice_pair_num[k];
    const int p0  = blockIdx.x * PPB;
    if (p0 >= n_k) return;
    __shared__ float w[D][D];
    __shared__ float f[PPB][D];
    for (int idx = threadIdx.x; idx < D * D; idx += 256) {
        int c = idx >> 5, d = idx & 31;
        w[c][d] = weight[d * (KOFF * D) + k * D + c];
    }
    const int pp = threadIdx.x >> 5;
    const int d  = threadIdx.x & 31;
    const int p  = p0 + pp;
    int orow = -1;
    if (p < n_k) {
        int irow = indice_pairs[(size_t)k * N_PTS + p];
        orow     = indice_pairs[(size_t)(KOFF + k) * N_PTS + p];
        f[pp][d] = feat[(size_t)irow * D + d];
    }
    __syncthreads();
    if (p < n_k) {
        float acc = 0.f;
#pragma unroll
        for (int c = 0; c < D; ++c) acc += f[pp][c] * w[c][d];
        atomicAdd(&out[(size_t)orow * D + d], acc);
    }
}

extern "C" void kernel_launch(void* const* d_in, const int* in_sizes, int n_in,
                              void* d_out, int out_size, void* d_ws, size_t ws_size,
                              hipStream_t stream) {
    const float* feat            = (const float*)d_in[0];
    const float* weight          = (const float*)d_in[1];
    const float* bias            = (const float*)d_in[2];
    const int*   indice_pairs    = (const int*)d_in[3];
    const int*   indice_pair_num = (const int*)d_in[4];
    float*       out             = (float*)d_out;

    const size_t CNTB  = (size_t)NXCD * BINS * KOFF * 4;      // 147,456
    const size_t HDR   = 151552;                              // counts + over_n
    const size_t BKT   = (size_t)NXCD * BINS * KOFF * SUBCAP * 4;  // 11.25 MiB
    const size_t OVERB = (size_t)OVER_CAP * 8;                // 1 MiB
    const size_t need  = HDR + BKT + OVERB;                   // ~12.4 MiB

    if (ws_size >= need) {
        int*          counts   = (int*)d_ws;
        int*          over_n   = (int*)((char*)d_ws + CNTB);
        unsigned int* buckets  = (unsigned int*)((char*)d_ws + HDR);
        uint2*        overlist = (uint2*)((char*)d_ws + HDR + BKT);

        hipMemsetAsync(d_ws, 0, HDR, stream);
        dim3 fgrid(N_PTS / 256, KOFF);
        fill_kernel<<<fgrid, 256, 0, stream>>>(indice_pairs, indice_pair_num,
                                               counts, buckets, overlist, over_n);
        phase2_kernel<<<BINS, 1024, 0, stream>>>(feat, weight, bias, counts,
                                                 buckets, out);
        overflow_kernel<<<64, 256, 0, stream>>>(feat, weight, overlist, over_n, out);
    } else {
        int n_vec4 = N_PTS * D / 4;
        bias_init_kernel<<<n_vec4 / 256, 256, 0, stream>>>(bias, out);
        dim3 grid((N_PTS + PPB - 1) / PPB, KOFF);
        scatter_conv_kernel<<<grid, 256, 0, stream>>>(
            feat, weight, indice_pairs, indice_pair_num, out);
    }
}

// Round 7
// 360.680 us; speedup vs baseline: 1.0769x; 1.0769x over previous
//
#include <hip/hip_runtime.h>

#define KOFF 9
#define N_PTS 262144
#define D 32
#define BINS 512
#define ROWS_PER_BIN 512       // N_PTS / BINS
#define TILE_ROWS 513          // + dump row for sentinel entries
#define CAP 640                // per (bin,k) bucket capacity
#define OVER_CAP 131072
#define SENT (512u << 18)

typedef __attribute__((ext_vector_type(4))) float f32x4;
typedef __attribute__((ext_vector_type(8))) short short8;

__device__ inline short f2bf(float f) {      // round-to-nearest-even f32->bf16
    unsigned u = __float_as_uint(f);
    u = (u + 0x7fffu + ((u >> 16) & 1u)) >> 16;
    return (short)u;
}

// ---------- feat f32 -> bf16 (streaming, 8 elems/thread) ----------
__global__ void __launch_bounds__(256)
convert_kernel(const float* __restrict__ feat, unsigned short* __restrict__ bfeat) {
    int i = blockIdx.x * 256 + threadIdx.x;
    const f32x4* f4 = (const f32x4*)feat;
    f32x4 a = f4[2 * i], b = f4[2 * i + 1];
    short8 o;
#pragma unroll
    for (int j = 0; j < 4; ++j) { o[j] = f2bf(a[j]); o[j + 4] = f2bf(b[j]); }
    *(short8*)(bfeat + (size_t)i * 8) = o;
}

// ---------- fill: bin pairs by (orow>>9, k); entry = irow | olow<<18 ----------
__global__ void __launch_bounds__(256)
fill_kernel(const int* __restrict__ indice_pairs,
            const int* __restrict__ indice_pair_num,
            int* __restrict__ counts,          // [BINS*KOFF]
            unsigned int* __restrict__ buckets,
            uint2* __restrict__ overlist,
            int* __restrict__ over_n) {
    const int k = blockIdx.y;
    const int n_k = indice_pair_num[k];
    if (blockIdx.x * 256 >= n_k) return;
    const int p = blockIdx.x * 256 + threadIdx.x;
    if (p >= n_k) return;
    int irow = indice_pairs[(size_t)k * N_PTS + p];
    int orow = indice_pairs[(size_t)(KOFF + k) * N_PTS + p];
    int bin = orow >> 9, olow = orow & 511;
    int b = bin * KOFF + k;
    int slot = atomicAdd(&counts[b], 1);
    if (slot < CAP) {
        buckets[(size_t)b * CAP + slot] = (unsigned)irow | ((unsigned)olow << 18);
    } else {
        int s2 = atomicAdd(over_n, 1);
        if (s2 < OVER_CAP) overlist[s2] = make_uint2((unsigned)irow | ((unsigned)k << 18),
                                                     (unsigned)orow);
    }
}

// ---------- phase 2: per-bin LDS-tile accumulate with MFMA ----------
// BF16=1: A-frag is one 16B load from bf16 feat (1 line per row gather).
// BF16=0: exact R5 path (2 f32x4 loads + f2bf), for the ws fallback tier.
template<int BF16>
__global__ void __launch_bounds__(512, 4)
phase2_kernel(const float* __restrict__ feat,
              const unsigned short* __restrict__ bfeat,
              const float* __restrict__ weight,
              const float* __restrict__ bias,
              const int* __restrict__ counts,
              const unsigned int* __restrict__ buckets,
              float* __restrict__ out) {
    __shared__ f32x4 tile4[TILE_ROWS * D / 4];      // 65,664 B accumulator
    float* tile = (float*)tile4;

    const int bin  = blockIdx.x;
    const int tid  = threadIdx.x;
    const int wave = tid >> 6;
    const int lane = tid & 63;

    f32x4 z = {0.f, 0.f, 0.f, 0.f};
    for (int i = tid; i < TILE_ROWS * D / 4; i += 512) tile4[i] = z;
    __syncthreads();

    const int arow = lane & 15;                 // A row / entry index within group
    const int hoff = (lane >> 4) << 3;          // k-dim chunk: 8 elems

#pragma unroll 1
    for (int k = 0; k < KOFF; ++k) {
        // B fragments: B[c=hoff+j][col=arow(+16)] = weight[col][k][c]
        short8 bf0, bf1;
        {
            const float* wp0 = weight + (size_t)arow * (KOFF * D) + k * D + hoff;
            const float* wp1 = wp0 + 16 * (KOFF * D);
            f32x4 w0 = *(const f32x4*)wp0, w1 = *(const f32x4*)(wp0 + 4);
            f32x4 w2 = *(const f32x4*)wp1, w3 = *(const f32x4*)(wp1 + 4);
#pragma unroll
            for (int j = 0; j < 4; ++j) {
                bf0[j] = f2bf(w0[j]); bf0[j + 4] = f2bf(w1[j]);
                bf1[j] = f2bf(w2[j]); bf1[j + 4] = f2bf(w3[j]);
            }
        }

        int cnt = counts[bin * KOFF + k];
        cnt = cnt < CAP ? cnt : CAP;
        const unsigned* bk = buckets + (size_t)(bin * KOFF + k) * CAP;
        int ngroups = (cnt + 15) >> 4;

        // depth-2 pipeline
        unsigned entA = SENT;
        short8 afA = {0, 0, 0, 0, 0, 0, 0, 0};
        f32x4 fa0 = z, fa1 = z;
        int g = wave;
        if (g < ngroups) {
            int ei = g * 16 + arow;
            entA = (ei < cnt) ? bk[ei] : SENT;
            if constexpr (BF16) {
                afA = *(const short8*)(bfeat + ((size_t)(entA & 0x3ffff) << 5) + hoff);
            } else {
                const float* fp = feat + ((size_t)(entA & 0x3ffff) << 5) + hoff;
                fa0 = *(const f32x4*)fp; fa1 = *(const f32x4*)(fp + 4);
            }
        }
#pragma unroll 1
        for (; g < ngroups; g += 8) {
            unsigned entB = SENT;
            short8 afB = {0, 0, 0, 0, 0, 0, 0, 0};
            f32x4 fb0 = z, fb1 = z;
            int gn = g + 8;
            if (gn < ngroups) {
                int ei = gn * 16 + arow;
                entB = (ei < cnt) ? bk[ei] : SENT;
                if constexpr (BF16) {
                    afB = *(const short8*)(bfeat + ((size_t)(entB & 0x3ffff) << 5) + hoff);
                } else {
                    const float* fp = feat + ((size_t)(entB & 0x3ffff) << 5) + hoff;
                    fb0 = *(const f32x4*)fp; fb1 = *(const f32x4*)(fp + 4);
                }
            }

            short8 af;
            if constexpr (BF16) {
                af = afA;
            } else {
#pragma unroll
                for (int j = 0; j < 4; ++j) { af[j] = f2bf(fa0[j]); af[j + 4] = f2bf(fa1[j]); }
            }

            f32x4 acc0 = __builtin_amdgcn_mfma_f32_16x16x32_bf16(af, bf0, z, 0, 0, 0);
            f32x4 acc1 = __builtin_amdgcn_mfma_f32_16x16x32_bf16(af, bf1, z, 0, 0, 0);

            // scatter C: row=(lane>>4)*4+rg entries, cols arow & arow+16
#pragma unroll
            for (int rg = 0; rg < 4; ++rg) {
                int crow = ((lane >> 4) << 2) + rg;
                int entc = __builtin_amdgcn_ds_bpermute(crow << 2, (int)entA);
                int rl   = ((unsigned)entc >> 18) & 0x3ff;
                int sw   = ((rl >> 2) & 1) << 4;
                atomicAdd(&tile[rl * D + (arow ^ sw)], acc0[rg]);
                atomicAdd(&tile[rl * D + ((arow + 16) ^ sw)], acc1[rg]);
            }
            entA = entB; afA = afB; fa0 = fb0; fa1 = fb1;
        }
    }
    __syncthreads();

    // stream tile + bias to out (coalesced, unswizzled)
    f32x4 b4 = ((const f32x4*)bias)[tid & 7];
    for (int i = tid; i < ROWS_PER_BIN * 8; i += 512) {
        int row = i >> 3, c4 = i & 7;
        int sc4 = c4 ^ (((row >> 2) & 1) << 2);     // f32x4-level unswizzle
        f32x4 v = tile4[row * 8 + sc4];
        v += b4;
        *(f32x4*)&out[((size_t)(bin * ROWS_PER_BIN + row)) * D + c4 * 4] = v;
    }
}

// ---------- rare overflow cleanup (after phase2 store) ----------
__global__ void overflow_kernel(const float* __restrict__ feat,
                                const float* __restrict__ weight,
                                const uint2* __restrict__ overlist,
                                const int* __restrict__ over_n,
                                float* __restrict__ out) {
    int n = *over_n;
    n = n < OVER_CAP ? n : OVER_CAP;
    for (int i = blockIdx.x * blockDim.x + threadIdx.x; i < n;
         i += gridDim.x * blockDim.x) {
        uint2 e = overlist[i];
        int irow = e.x & 0x3ffff, k = (e.x >> 18) & 15, orow = (int)e.y;
        float fr[D];
#pragma unroll
        for (int c = 0; c < D; c += 4)
            *(f32x4*)&fr[c] = *(const f32x4*)&feat[(size_t)irow * D + c];
#pragma unroll 1
        for (int dd = 0; dd < D; ++dd) {
            float a = 0.f;
#pragma unroll
            for (int c = 0; c < D; ++c)
                a += fr[c] * weight[dd * (KOFF * D) + k * D + c];
            atomicAdd(&out[(size_t)orow * D + dd], a);
        }
    }
}

// ---------- fallback path (R1): direct scatter with global atomics ----------
__global__ void bias_init_kernel(const float* __restrict__ bias,
                                 float* __restrict__ out) {
    int i = blockIdx.x * blockDim.x + threadIdx.x;
    float4 b = ((const float4*)bias)[i & 7];
    ((float4*)out)[i] = b;
}

#define PPB 8
__global__ void __launch_bounds__(256)
scatter_conv_kernel(const float* __restrict__ feat,
                    const float* __restrict__ weight,
                    const int* __restrict__ indice_pairs,
                    const int* __restrict__ indice_pair_num,
                    float* __restrict__ out) {
    const int k   = blockIdx.y;
    const int n_k = indice_pair_num[k];
    const int p0  = blockIdx.x * PPB;
    if (p0 >= n_k) return;
    __shared__ float w[D][D];
    __shared__ float f[PPB][D];
    for (int idx = threadIdx.x; idx < D * D; idx += 256) {
        int c = idx >> 5, d = idx & 31;
        w[c][d] = weight[d * (KOFF * D) + k * D + c];
    }
    const int pp = threadIdx.x >> 5;
    const int d  = threadIdx.x & 31;
    const int p  = p0 + pp;
    int orow = -1;
    if (p < n_k) {
        int irow = indice_pairs[(size_t)k * N_PTS + p];
        orow     = indice_pairs[(size_t)(KOFF + k) * N_PTS + p];
        f[pp][d] = feat[(size_t)irow * D + d];
    }
    __syncthreads();
    if (p < n_k) {
        float acc = 0.f;
#pragma unroll
        for (int c = 0; c < D; ++c) acc += f[pp][c] * w[c][d];
        atomicAdd(&out[(size_t)orow * D + d], acc);
    }
}

extern "C" void kernel_launch(void* const* d_in, const int* in_sizes, int n_in,
                              void* d_out, int out_size, void* d_ws, size_t ws_size,
                              hipStream_t stream) {
    const float* feat            = (const float*)d_in[0];
    const float* weight          = (const float*)d_in[1];
    const float* bias            = (const float*)d_in[2];
    const int*   indice_pairs    = (const int*)d_in[3];
    const int*   indice_pair_num = (const int*)d_in[4];
    float*       out             = (float*)d_out;

    const size_t HDR   = 32768;                           // counts(18,432) + over_n
    const size_t BKT   = (size_t)BINS * KOFF * CAP * 4;   // 11.25 MiB
    const size_t OVERB = (size_t)OVER_CAP * 8;            // 1 MiB
    const size_t FEATB = (size_t)N_PTS * D * 2;           // 16 MiB bf16 feat
    const size_t need_bf  = FEATB + HDR + BKT + OVERB;    // ~28.3 MiB
    const size_t need_f32 = HDR + BKT + OVERB;            // ~12.3 MiB

    if (ws_size >= need_bf) {
        unsigned short* bfeat = (unsigned short*)d_ws;
        char* base = (char*)d_ws + FEATB;
        int*          counts   = (int*)base;
        int*          over_n   = (int*)(base + 20480);
        unsigned int* buckets  = (unsigned int*)(base + HDR);
        uint2*        overlist = (uint2*)(base + HDR + BKT);

        hipMemsetAsync(base, 0, HDR, stream);
        convert_kernel<<<N_PTS * D / 8 / 256, 256, 0, stream>>>(feat, bfeat);
        dim3 fgrid(N_PTS / 256, KOFF);
        fill_kernel<<<fgrid, 256, 0, stream>>>(indice_pairs, indice_pair_num,
                                               counts, buckets, overlist, over_n);
        phase2_kernel<1><<<BINS, 512, 0, stream>>>(feat, bfeat, weight, bias,
                                                   counts, buckets, out);
        overflow_kernel<<<64, 256, 0, stream>>>(feat, weight, overlist, over_n, out);
    } else if (ws_size >= need_f32) {
        int*          counts   = (int*)d_ws;
        int*          over_n   = (int*)((char*)d_ws + 20480);
        unsigned int* buckets  = (unsigned int*)((char*)d_ws + HDR);
        uint2*        overlist = (uint2*)((char*)d_ws + HDR + BKT);

        hipMemsetAsync(d_ws, 0, HDR, stream);
        dim3 fgrid(N_PTS / 256, KOFF);
        fill_kernel<<<fgrid, 256, 0, stream>>>(indice_pairs, indice_pair_num,
                                               counts, buckets, overlist, over_n);
        phase2_kernel<0><<<BINS, 512, 0, stream>>>(feat, nullptr, weight, bias,
                                                   counts, buckets, out);
        overflow_kernel<<<64, 256, 0, stream>>>(feat, weight, overlist, over_n, out);
    } else {
        int n_vec4 = N_PTS * D / 4;
        bias_init_kernel<<<n_vec4 / 256, 256, 0, stream>>>(bias, out);
        dim3 grid((N_PTS + PPB - 1) / PPB, KOFF);
        scatter_conv_kernel<<<grid, 256, 0, stream>>>(
            feat, weight, indice_pairs, indice_pair_num, out);
    }
}